// Round 1
// baseline (2692.617 us; speedup 1.0000x reference)
//
#include <hip/hip_runtime.h>
#include <stdint.h>

#define NTOK 2048
#define DM   2048
#define NH   32
#define NKV  8
#define HDIM 64
#define NE   8
#define FI   7168

#define LOSCALE     2048.0f
#define INV_LOSCALE 0.00048828125f

typedef _Float16       f16x8 __attribute__((ext_vector_type(8)));
typedef unsigned short u16x8 __attribute__((ext_vector_type(8)));
typedef unsigned short u16x4 __attribute__((ext_vector_type(4)));
typedef float          f32x4 __attribute__((ext_vector_type(4)));

__device__ __forceinline__ unsigned short h_bits(_Float16 h) {
  union { _Float16 h; unsigned short u; } x; x.h = h; return x.u;
}
__device__ __forceinline__ float h_val(unsigned short u) {
  union { unsigned short u; _Float16 h; } x; x.u = u; return (float)x.h;
}
// split v = hi + lo/2048, both fp16. lo scaled by 2048 to stay out of fp16 denormals.
__device__ __forceinline__ void fsplit(float v, unsigned short& hb, unsigned short& lb) {
  _Float16 h = (_Float16)v;
  _Float16 l = (_Float16)((v - (float)h) * LOSCALE);
  hb = h_bits(h); lb = h_bits(l);
}

// ---------------- RMSNorm: fp32 in -> f16 (OUT=0) or f16 hi/lo pair (OUT=1) ----
template<int OUT>
__global__ __launch_bounds__(256) void rmsnorm_kernel(
    const float* __restrict__ x, const float* __restrict__ w,
    unsigned short* __restrict__ o0, unsigned short* __restrict__ o1)
{
  int t = blockIdx.x, tid = threadIdx.x;
  const float4* xr = (const float4*)(x + (size_t)t * DM);
  float4 a = xr[tid], b = xr[tid + 256];
  float ssq = a.x*a.x + a.y*a.y + a.z*a.z + a.w*a.w
            + b.x*b.x + b.y*b.y + b.z*b.z + b.w*b.w;
  #pragma unroll
  for (int m = 1; m < 64; m <<= 1) ssq += __shfl_xor(ssq, m);
  __shared__ float sred[4];
  if ((tid & 63) == 0) sred[tid >> 6] = ssq;
  __syncthreads();
  float tot = sred[0] + sred[1] + sred[2] + sred[3];
  float rs = 1.0f / sqrtf(tot * (1.0f / DM) + 1e-5f);
  const float4* wr = (const float4*)w;
  float4 wa = wr[tid], wb = wr[tid + 256];
  float v[8] = { a.x*rs*wa.x, a.y*rs*wa.y, a.z*rs*wa.z, a.w*rs*wa.w,
                 b.x*rs*wb.x, b.y*rs*wb.y, b.z*rs*wb.z, b.w*rs*wb.w };
  size_t base0 = (size_t)t * DM + tid * 4;
  size_t base1 = base0 + 1024;
  if (OUT == 0) {
    u16x4 p0, p1;
    #pragma unroll
    for (int j = 0; j < 4; ++j) { p0[j] = h_bits((_Float16)v[j]); p1[j] = h_bits((_Float16)v[4+j]); }
    *(u16x4*)(o0 + base0) = p0;
    *(u16x4*)(o0 + base1) = p1;
  } else {
    u16x4 h0, h1, l0, l1;
    #pragma unroll
    for (int j = 0; j < 4; ++j) {
      unsigned short hb, lb;
      fsplit(v[j], hb, lb);   h0[j] = hb; l0[j] = lb;
      fsplit(v[4+j], hb, lb); h1[j] = hb; l1[j] = lb;
    }
    *(u16x4*)(o0 + base0) = h0; *(u16x4*)(o0 + base1) = h1;
    *(u16x4*)(o1 + base0) = l0; *(u16x4*)(o1 + base1) = l1;
  }
}

// ---------------- GEMM: C[M,N] = A[M,K] * B[K,N], B is fp32 global (weights) ----
// MODE 0: A = f16 single plane, 1 MFMA/pair. MODE 1: A = f16 hi/lo, 3 MFMA (split).
// EPI 0: store f16 C0.  EPI 2: store fp32 C0 = resid + acc.  EPI 3: store f16 split C0/C1.
// cnt/offs non-null => expert mode (blockIdx.z = expert, rows = cnt[e], C rows offset by offs[e]).
// tok non-null => A rows gathered via tok[offs[e]+row].
template<int MODE, int EPI>
__global__ __launch_bounds__(256, 2) void gemm_kernel(
    const unsigned short* __restrict__ Ah, const unsigned short* __restrict__ Al, int lda,
    const float* __restrict__ B, int ldb, long bstride,
    void* __restrict__ C0, void* __restrict__ C1, int ldc,
    const float* __restrict__ resid, int M, int K,
    const int* __restrict__ cnt, const int* __restrict__ offsp,
    const int* __restrict__ tok)
{
  // LDS: [k/8][row][8] so A and B fragments are contiguous ds_read_b128.
  __shared__ unsigned short AsH[4][128][8];
  __shared__ unsigned short BsH[4][128][8];
  __shared__ unsigned short AsL[MODE ? 4 : 1][128][8];
  __shared__ unsigned short BsL[MODE ? 4 : 1][128][8];

  int e = blockIdx.z;
  int Me = M, rbase = 0;
  if (cnt) { Me = cnt[e]; rbase = offsp[e]; }
  int mt = blockIdx.y, nt = blockIdx.x;
  if (mt * 128 >= Me) return;
  int tid = threadIdx.x;
  const float* Bp = B + (long)e * bstride + nt * 128;

  // A staging: 2 threads per row, each 2x u16x8 (16B) loads.
  int ar = tid >> 1;
  int gr = mt * 128 + ar;
  bool aval = (gr < Me);
  long arow = 0;
  if (aval) arow = tok ? (long)tok[rbase + gr] : (long)(rbase + gr);
  const unsigned short* ApH = Ah + arow * (long)lda;
  const unsigned short* ApL = MODE ? (Al + arow * (long)lda) : Ah;

  // B staging: thread -> column n_, k pairs (transpose+convert fp32->f16 into LDS).
  int n_ = tid & 127, g_ = tid >> 7;
  const float* Bc = Bp + n_;

  int lane = tid & 63, wv = tid >> 6;
  int wm = (wv & 1) * 64, wn = (wv >> 1) * 64;
  int l15 = lane & 15, quad = lane >> 4;

  f32x4 acc[4][4]  = {};
  f32x4 acc2[4][4] = {};   // scaled cross terms (MODE 1)

  for (int k0 = 0; k0 < K; k0 += 32) {
    __syncthreads();
    #pragma unroll
    for (int c = 0; c < 2; ++c) {
      int oct = (tid & 1) * 2 + c;
      u16x8 vh = {0,0,0,0,0,0,0,0};
      if (aval) vh = *(const u16x8*)(ApH + k0 + oct * 8);
      *(u16x8*)&AsH[oct][ar][0] = vh;
      if (MODE) {
        u16x8 vl = {0,0,0,0,0,0,0,0};
        if (aval) vl = *(const u16x8*)(ApL + k0 + oct * 8);
        *(u16x8*)&AsL[oct][ar][0] = vl;
      }
    }
    #pragma unroll
    for (int p = 0; p < 8; ++p) {
      int kk = g_ * 16 + 2 * p;
      float f0 = Bc[(long)(k0 + kk) * ldb];
      float f1 = Bc[(long)(k0 + kk + 1) * ldb];
      if (MODE == 0) {
        unsigned pk = (unsigned)h_bits((_Float16)f0) | ((unsigned)h_bits((_Float16)f1) << 16);
        *(unsigned*)&BsH[kk >> 3][n_][kk & 7] = pk;
      } else {
        unsigned short h0, l0, h1, l1;
        fsplit(f0, h0, l0); fsplit(f1, h1, l1);
        *(unsigned*)&BsH[kk >> 3][n_][kk & 7] = (unsigned)h0 | ((unsigned)h1 << 16);
        *(unsigned*)&BsL[kk >> 3][n_][kk & 7] = (unsigned)l0 | ((unsigned)l1 << 16);
      }
    }
    __syncthreads();
    if (MODE == 0) {
      f16x8 af[4], bfr[4];
      #pragma unroll
      for (int i = 0; i < 4; ++i) af[i] = *(const f16x8*)&AsH[quad][wm + i*16 + l15][0];
      #pragma unroll
      for (int j = 0; j < 4; ++j) bfr[j] = *(const f16x8*)&BsH[quad][wn + j*16 + l15][0];
      #pragma unroll
      for (int i = 0; i < 4; ++i)
        #pragma unroll
        for (int j = 0; j < 4; ++j)
          acc[i][j] = __builtin_amdgcn_mfma_f32_16x16x32_f16(af[i], bfr[j], acc[i][j], 0, 0, 0);
    } else {
      f16x8 ah[4], al[4], bh[4], bl[4];
      #pragma unroll
      for (int i = 0; i < 4; ++i) {
        ah[i] = *(const f16x8*)&AsH[quad][wm + i*16 + l15][0];
        al[i] = *(const f16x8*)&AsL[quad][wm + i*16 + l15][0];
      }
      #pragma unroll
      for (int j = 0; j < 4; ++j) {
        bh[j] = *(const f16x8*)&BsH[quad][wn + j*16 + l15][0];
        bl[j] = *(const f16x8*)&BsL[quad][wn + j*16 + l15][0];
      }
      #pragma unroll
      for (int i = 0; i < 4; ++i)
        #pragma unroll
        for (int j = 0; j < 4; ++j) {
          acc[i][j]  = __builtin_amdgcn_mfma_f32_16x16x32_f16(ah[i], bh[j], acc[i][j], 0, 0, 0);
          acc2[i][j] = __builtin_amdgcn_mfma_f32_16x16x32_f16(ah[i], bl[j], acc2[i][j], 0, 0, 0);
          acc2[i][j] = __builtin_amdgcn_mfma_f32_16x16x32_f16(al[i], bh[j], acc2[i][j], 0, 0, 0);
        }
    }
  }
  // epilogue: C/D layout col=lane&15, row=quad*4+reg
  #pragma unroll
  for (int i = 0; i < 4; ++i) {
    #pragma unroll
    for (int r = 0; r < 4; ++r) {
      int lrow = wm + i*16 + quad*4 + r;
      int growc = mt*128 + lrow;
      if (growc < Me) {
        long crow = rbase + growc;
        #pragma unroll
        for (int j = 0; j < 4; ++j) {
          int col = nt*128 + wn + j*16 + l15;
          float vacc = acc[i][j][r];
          if (MODE) vacc += acc2[i][j][r] * INV_LOSCALE;
          if (EPI == 0) {
            ((unsigned short*)C0)[crow * (long)ldc + col] = h_bits((_Float16)vacc);
          } else if (EPI == 2) {
            ((float*)C0)[crow * (long)ldc + col] = vacc + resid[crow * (long)ldc + col];
          } else {
            unsigned short hb, lb; fsplit(vacc, hb, lb);
            ((unsigned short*)C0)[crow * (long)ldc + col] = hb;
            ((unsigned short*)C1)[crow * (long)ldc + col] = lb;
          }
        }
      }
    }
  }
}

// ---------------- RoPE (in-place on q/k hi/lo planes), fp32 math -----------------
__global__ __launch_bounds__(256) void rope_kernel(
    unsigned short* __restrict__ qh_, unsigned short* __restrict__ ql_,
    unsigned short* __restrict__ kh_, unsigned short* __restrict__ kl_,
    const int* __restrict__ pos)
{
  int t = blockIdx.x, tid = threadIdx.x;
  float p = (float)pos[t];
  #pragma unroll
  for (int it = 0; it < 5; ++it) {
    int idx = tid + it * 256;  // 0..1023 -> q (32h x 32 pairs), 1024..1279 -> k (8h x 32)
    unsigned short *bh, *bl;
    int hh, ii;
    if (idx < 1024) {
      bh = qh_ + (size_t)t * (NH*HDIM); bl = ql_ + (size_t)t * (NH*HDIM);
      hh = idx >> 5; ii = idx & 31;
    } else {
      int j2 = idx - 1024;
      bh = kh_ + (size_t)t * (NKV*HDIM); bl = kl_ + (size_t)t * (NKV*HDIM);
      hh = j2 >> 5; ii = j2 & 31;
    }
    // inv = 1e6^(-2*ii/64), double-accurate then rounded to fp32 (match np fp32 value)
    float inv = (float)exp((double)(-2 * ii) * (13.815510557964274 / 64.0));
    float ang = p * inv;
    float sn = sinf(ang), cs = cosf(ang);
    int o1 = hh * 64 + ii, o2 = o1 + 32;
    float x1 = h_val(bh[o1]) + h_val(bl[o1]) * INV_LOSCALE;
    float x2 = h_val(bh[o2]) + h_val(bl[o2]) * INV_LOSCALE;
    float y1 = x1 * cs - x2 * sn;
    float y2 = x2 * cs + x1 * sn;
    unsigned short hb, lb;
    fsplit(y1, hb, lb); bh[o1] = hb; bl[o1] = lb;
    fsplit(y2, hb, lb); bh[o2] = hb; bl[o2] = lb;
  }
}

// ---------------- Flash attention (causal, GQA), fp16x2 split, online softmax ----
__global__ __launch_bounds__(256, 2) void flash_kernel(
    const unsigned short* __restrict__ qh_, const unsigned short* __restrict__ ql_,
    const unsigned short* __restrict__ kh_, const unsigned short* __restrict__ kl_,
    const unsigned short* __restrict__ vh_, const unsigned short* __restrict__ vl_,
    unsigned short* __restrict__ aoh, unsigned short* __restrict__ aol)
{
  __shared__ unsigned short Qh[64][72], Ql[64][72];
  __shared__ unsigned short Kh[64][72], Kl[64][72];
  __shared__ unsigned short Vh[64][72], Vl[64][72];     // V transposed: [hd][key]
  __shared__ unsigned short Ph[4][16][72], Pl[4][16][72];
  int qt = blockIdx.x, h = blockIdx.y, kvh = h >> 2;
  int tid = threadIdx.x, lane = tid & 63, wv = tid >> 6;
  int l15 = lane & 15, quad = lane >> 4;
  #pragma unroll
  for (int c = 0; c < 2; ++c) {
    int chunk = tid + 256 * c, r = chunk >> 3, oct = chunk & 7;
    size_t goff = (size_t)(qt*64 + r) * (NH*HDIM) + h*HDIM + oct*8;
    *(u16x8*)&Qh[r][oct*8] = *(const u16x8*)(qh_ + goff);
    *(u16x8*)&Ql[r][oct*8] = *(const u16x8*)(ql_ + goff);
  }
  f32x4 O1[4] = {}, O2[4] = {};
  f32x4 m_st = {-1e30f, -1e30f, -1e30f, -1e30f};
  f32x4 l_st = {};
  for (int kt = 0; kt <= qt; ++kt) {
    __syncthreads();
    #pragma unroll
    for (int c = 0; c < 2; ++c) {
      int chunk = tid + 256 * c, r = chunk >> 3, oct = chunk & 7;
      size_t goff = (size_t)(kt*64 + r) * (NKV*HDIM) + kvh*HDIM + oct*8;
      *(u16x8*)&Kh[r][oct*8] = *(const u16x8*)(kh_ + goff);
      *(u16x8*)&Kl[r][oct*8] = *(const u16x8*)(kl_ + goff);
      u16x8 vvh = *(const u16x8*)(vh_ + goff);
      u16x8 vvl = *(const u16x8*)(vl_ + goff);
      #pragma unroll
      for (int j = 0; j < 8; ++j) { Vh[oct*8+j][r] = vvh[j]; Vl[oct*8+j][r] = vvl[j]; }
    }
    __syncthreads();
    f32x4 S1[4] = {}, S2[4] = {};
    #pragma unroll
    for (int ks = 0; ks < 2; ++ks) {
      f16x8 aqh = *(const f16x8*)&Qh[wv*16 + l15][ks*32 + quad*8];
      f16x8 aql = *(const f16x8*)&Ql[wv*16 + l15][ks*32 + quad*8];
      #pragma unroll
      for (int n2 = 0; n2 < 4; ++n2) {
        f16x8 bkh = *(const f16x8*)&Kh[n2*16 + l15][ks*32 + quad*8];
        f16x8 bkl = *(const f16x8*)&Kl[n2*16 + l15][ks*32 + quad*8];
        S1[n2] = __builtin_amdgcn_mfma_f32_16x16x32_f16(aqh, bkh, S1[n2], 0, 0, 0);
        S2[n2] = __builtin_amdgcn_mfma_f32_16x16x32_f16(aqh, bkl, S2[n2], 0, 0, 0);
        S2[n2] = __builtin_amdgcn_mfma_f32_16x16x32_f16(aql, bkh, S2[n2], 0, 0, 0);
      }
    }
    bool diag = (kt == qt);
    float Sv[4][4];
    #pragma unroll
    for (int n2 = 0; n2 < 4; ++n2)
      #pragma unroll
      for (int r = 0; r < 4; ++r) {
        float s = (S1[n2][r] + S2[n2][r] * INV_LOSCALE) * 0.125f;
        if (diag && (n2*16 + l15) > (wv*16 + quad*4 + r)) s = -1e30f;
        Sv[n2][r] = s;
      }
    f32x4 mx;
    #pragma unroll
    for (int r = 0; r < 4; ++r)
      mx[r] = fmaxf(fmaxf(Sv[0][r], Sv[1][r]), fmaxf(Sv[2][r], Sv[3][r]));
    #pragma unroll
    for (int msk = 1; msk < 16; msk <<= 1)
      #pragma unroll
      for (int r = 0; r < 4; ++r) mx[r] = fmaxf(mx[r], __shfl_xor(mx[r], msk));
    f32x4 mnew, alpha;
    #pragma unroll
    for (int r = 0; r < 4; ++r) {
      mnew[r] = fmaxf(m_st[r], mx[r]);
      alpha[r] = __expf(m_st[r] - mnew[r]);
      m_st[r] = mnew[r];
    }
    f32x4 rsum = {};
    #pragma unroll
    for (int n2 = 0; n2 < 4; ++n2)
      #pragma unroll
      for (int r = 0; r < 4; ++r) {
        float pp = __expf(Sv[n2][r] - mnew[r]);
        rsum[r] += pp;
        unsigned short hb, lb; fsplit(pp, hb, lb);
        Ph[wv][quad*4 + r][n2*16 + l15] = hb;
        Pl[wv][quad*4 + r][n2*16 + l15] = lb;
      }
    #pragma unroll
    for (int msk = 1; msk < 16; msk <<= 1)
      #pragma unroll
      for (int r = 0; r < 4; ++r) rsum[r] += __shfl_xor(rsum[r], msk);
    #pragma unroll
    for (int r = 0; r < 4; ++r) l_st[r] = l_st[r] * alpha[r] + rsum[r];
    #pragma unroll
    for (int n2 = 0; n2 < 4; ++n2)
      #pragma unroll
      for (int r = 0; r < 4; ++r) { O1[n2][r] *= alpha[r]; O2[n2][r] *= alpha[r]; }
    #pragma unroll
    for (int ks = 0; ks < 2; ++ks) {
      f16x8 aph = *(const f16x8*)&Ph[wv][l15][ks*32 + quad*8];
      f16x8 apl = *(const f16x8*)&Pl[wv][l15][ks*32 + quad*8];
      #pragma unroll
      for (int n2 = 0; n2 < 4; ++n2) {
        f16x8 bvh = *(const f16x8*)&Vh[n2*16 + l15][ks*32 + quad*8];
        f16x8 bvl = *(const f16x8*)&Vl[n2*16 + l15][ks*32 + quad*8];
        O1[n2] = __builtin_amdgcn_mfma_f32_16x16x32_f16(aph, bvh, O1[n2], 0, 0, 0);
        O2[n2] = __builtin_amdgcn_mfma_f32_16x16x32_f16(aph, bvl, O2[n2], 0, 0, 0);
        O2[n2] = __builtin_amdgcn_mfma_f32_16x16x32_f16(apl, bvh, O2[n2], 0, 0, 0);
      }
    }
  }
  #pragma unroll
  for (int n2 = 0; n2 < 4; ++n2)
    #pragma unroll
    for (int r = 0; r < 4; ++r) {
      float val = (O1[n2][r] + O2[n2][r] * INV_LOSCALE) / l_st[r];
      int row = qt*64 + wv*16 + quad*4 + r;
      int col = h*HDIM + n2*16 + l15;
      unsigned short hb, lb; fsplit(val, hb, lb);
      aoh[(size_t)row * (NH*HDIM) + col] = hb;
      aol[(size_t)row * (NH*HDIM) + col] = lb;
    }
}

// ---------------- Router: fp32 logits from fp32 h2, top-2, renormalized ----------
__global__ __launch_bounds__(256) void router_kernel(
    const float* __restrict__ h2, const float* __restrict__ w2,
    const float* __restrict__ Wr, int* __restrict__ ti, float* __restrict__ tw,
    int* __restrict__ cnt)
{
  int t = blockIdx.x, tid = threadIdx.x;
  const float* xr = h2 + (size_t)t * DM;
  float acc[8] = {0,0,0,0,0,0,0,0};
  float ssq = 0.f;
  for (int i = 0; i < 8; ++i) {
    int d = tid + i * 256;
    float hv = xr[d];
    float hw = hv * w2[d];
    ssq += hv * hv;
    const float4* wr4 = (const float4*)(Wr + (size_t)d * 8);
    float4 wa = wr4[0], wb = wr4[1];
    acc[0] += hw*wa.x; acc[1] += hw*wa.y; acc[2] += hw*wa.z; acc[3] += hw*wa.w;
    acc[4] += hw*wb.x; acc[5] += hw*wb.y; acc[6] += hw*wb.z; acc[7] += hw*wb.w;
  }
  #pragma unroll
  for (int msk = 1; msk < 64; msk <<= 1) {
    ssq += __shfl_xor(ssq, msk);
    #pragma unroll
    for (int e2 = 0; e2 < 8; ++e2) acc[e2] += __shfl_xor(acc[e2], msk);
  }
  __shared__ float red[4][9];
  if ((tid & 63) == 0) {
    #pragma unroll
    for (int e2 = 0; e2 < 8; ++e2) red[tid >> 6][e2] = acc[e2];
    red[tid >> 6][8] = ssq;
  }
  __syncthreads();
  if (tid == 0) {
    float s2 = red[0][8] + red[1][8] + red[2][8] + red[3][8];
    float rs = 1.0f / sqrtf(s2 * (1.0f / DM) + 1e-5f);
    float l[8];
    #pragma unroll
    for (int e2 = 0; e2 < 8; ++e2)
      l[e2] = (red[0][e2] + red[1][e2] + red[2][e2] + red[3][e2]) * rs;
    int i0 = 0;
    #pragma unroll
    for (int e2 = 1; e2 < 8; ++e2) if (l[e2] > l[i0]) i0 = e2;
    int i1 = (i0 == 0) ? 1 : 0;
    #pragma unroll
    for (int e2 = 0; e2 < 8; ++e2) if (e2 != i0 && l[e2] > l[i1]) i1 = e2;
    float p1 = __expf(l[i1] - l[i0]);
    float w0 = 1.0f / (1.0f + p1), w1 = p1 / (1.0f + p1);
    ti[t*2] = i0; ti[t*2+1] = i1;
    tw[t*2] = w0; tw[t*2+1] = w1;
    atomicAdd(&cnt[i0], 1);
    atomicAdd(&cnt[i1], 1);
  }
}

__global__ void offs_kernel(const int* __restrict__ cnt, int* __restrict__ offs) {
  if (threadIdx.x == 0) {
    int a = 0;
    for (int e = 0; e < NE; ++e) { offs[e] = a; a += cnt[e]; }
    offs[NE] = a;
  }
}

__global__ __launch_bounds__(256) void assign_kernel(
    const int* __restrict__ ti, const float* __restrict__ tw,
    const int* __restrict__ offs, int* __restrict__ cnt2,
    int* __restrict__ tok, int* __restrict__ slot_of)
{
  int t = blockIdx.x * 256 + threadIdx.x;
  if (t >= NTOK) return;
  for (int kk = 0; kk < 2; ++kk) {
    int e = ti[t*2 + kk];
    int p = atomicAdd(&cnt2[e], 1);
    int slot = offs[e] + p;
    tok[slot] = t;
    slot_of[t*2 + kk] = slot;
  }
  (void)tw;
}

// ---------------- act = silu(gate) * up, f16 in-place into gate ------------------
__global__ __launch_bounds__(256) void silu_kernel(
    unsigned short* __restrict__ gate, const unsigned short* __restrict__ up)
{
  size_t i = ((size_t)blockIdx.x * 256 + threadIdx.x) * 8;
  u16x8 g = *(u16x8*)(gate + i);
  u16x8 u = *(const u16x8*)(up + i);
  u16x8 o;
  #pragma unroll
  for (int j = 0; j < 8; ++j) {
    float gf = h_val(g[j]), uf = h_val(u[j]);
    float a = gf / (1.0f + __expf(-gf)) * uf;
    o[j] = h_bits((_Float16)a);
  }
  *(u16x8*)(gate + i) = o;
}

// ---------------- out = h2 + w0*down[slot0] + w1*down[slot1] ---------------------
__global__ __launch_bounds__(256) void final_kernel(
    const float* __restrict__ h2, const unsigned short* __restrict__ down,
    const int* __restrict__ slot_of, const float* __restrict__ tw,
    float* __restrict__ out)
{
  int t = blockIdx.x, tid = threadIdx.x;
  int s0 = slot_of[t*2], s1 = slot_of[t*2 + 1];
  float w0 = tw[t*2], w1 = tw[t*2 + 1];
  u16x8 d0 = *(const u16x8*)(down + (size_t)s0 * DM + tid * 8);
  u16x8 d1 = *(const u16x8*)(down + (size_t)s1 * DM + tid * 8);
  const float4* h4 = (const float4*)(h2 + (size_t)t * DM);
  float4 a = h4[tid*2], b = h4[tid*2 + 1];
  float4 oa, ob;
  oa.x = a.x + w0*h_val(d0[0]) + w1*h_val(d1[0]);
  oa.y = a.y + w0*h_val(d0[1]) + w1*h_val(d1[1]);
  oa.z = a.z + w0*h_val(d0[2]) + w1*h_val(d1[2]);
  oa.w = a.w + w0*h_val(d0[3]) + w1*h_val(d1[3]);
  ob.x = b.x + w0*h_val(d0[4]) + w1*h_val(d1[4]);
  ob.y = b.y + w0*h_val(d0[5]) + w1*h_val(d1[5]);
  ob.z = b.z + w0*h_val(d0[6]) + w1*h_val(d1[6]);
  ob.w = b.w + w0*h_val(d0[7]) + w1*h_val(d1[7]);
  float4* o4 = (float4*)(out + (size_t)t * DM);
  o4[tid*2] = oa; o4[tid*2 + 1] = ob;
}

// ---------------- host ----------------
extern "C" void kernel_launch(void* const* d_in, const int* in_sizes, int n_in,
                              void* d_out, int out_size, void* d_ws, size_t ws_size,
                              hipStream_t stream) {
  (void)in_sizes; (void)n_in; (void)out_size; (void)ws_size;
  const float* hidden = (const float*)d_in[0];
  const int*   pos    = (const int*)d_in[1];
  const float* ln1w   = (const float*)d_in[2];
  const float* Wq     = (const float*)d_in[3];
  const float* Wk     = (const float*)d_in[4];
  const float* Wv     = (const float*)d_in[5];
  const float* Wo     = (const float*)d_in[6];
  const float* ln2w   = (const float*)d_in[7];
  const float* Wr     = (const float*)d_in[8];
  const float* W1     = (const float*)d_in[9];
  const float* W3     = (const float*)d_in[10];
  const float* W2     = (const float*)d_in[11];
  float* out = (float*)d_out;

  char* ws = (char*)d_ws;
  size_t off = 0;
  auto alloc = [&](size_t bytes) -> char* {
    char* p = ws + off;
    off += (bytes + 255) & ~(size_t)255;
    return p;
  };
  unsigned short* hn1h = (unsigned short*)alloc((size_t)NTOK * DM * 2);
  unsigned short* hn1l = (unsigned short*)alloc((size_t)NTOK * DM * 2);
  unsigned short* qh   = (unsigned short*)alloc((size_t)NTOK * NH * HDIM * 2);
  unsigned short* ql   = (unsigned short*)alloc((size_t)NTOK * NH * HDIM * 2);
  unsigned short* kh   = (unsigned short*)alloc((size_t)NTOK * NKV * HDIM * 2);
  unsigned short* kl   = (unsigned short*)alloc((size_t)NTOK * NKV * HDIM * 2);
  unsigned short* vh   = (unsigned short*)alloc((size_t)NTOK * NKV * HDIM * 2);
  unsigned short* vl   = (unsigned short*)alloc((size_t)NTOK * NKV * HDIM * 2);
  unsigned short* aoh  = (unsigned short*)alloc((size_t)NTOK * DM * 2);
  unsigned short* aol  = (unsigned short*)alloc((size_t)NTOK * DM * 2);
  float*          h2   = (float*)alloc((size_t)NTOK * DM * 4);
  unsigned short* hn2  = (unsigned short*)alloc((size_t)NTOK * DM * 2);
  unsigned short* gate_c = (unsigned short*)alloc((size_t)2 * NTOK * FI * 2);
  unsigned short* up_c   = (unsigned short*)alloc((size_t)2 * NTOK * FI * 2);
  unsigned short* down_c = (unsigned short*)alloc((size_t)2 * NTOK * DM * 2);
  int*   ti      = (int*)alloc(2 * NTOK * 4);
  float* tw      = (float*)alloc(2 * NTOK * 4);
  int*   tokl    = (int*)alloc(2 * NTOK * 4);
  int*   slot_of = (int*)alloc(2 * NTOK * 4);
  int*   cnt     = (int*)alloc(16 * 4);
  int*   cnt2    = cnt + 8;
  int*   offs    = (int*)alloc(9 * 4);

  dim3 blk(256);
  hipMemsetAsync(cnt, 0, 16 * sizeof(int), stream);

  rmsnorm_kernel<1><<<NTOK, blk, 0, stream>>>(hidden, ln1w, hn1h, hn1l);

  gemm_kernel<1,3><<<dim3(16,16,1), blk, 0, stream>>>(hn1h, hn1l, DM, Wq, DM, 0,
      qh, ql, DM, nullptr, NTOK, DM, nullptr, nullptr, nullptr);
  gemm_kernel<1,3><<<dim3(4,16,1), blk, 0, stream>>>(hn1h, hn1l, DM, Wk, NKV*HDIM, 0,
      kh, kl, NKV*HDIM, nullptr, NTOK, DM, nullptr, nullptr, nullptr);
  gemm_kernel<1,3><<<dim3(4,16,1), blk, 0, stream>>>(hn1h, hn1l, DM, Wv, NKV*HDIM, 0,
      vh, vl, NKV*HDIM, nullptr, NTOK, DM, nullptr, nullptr, nullptr);

  rope_kernel<<<NTOK, blk, 0, stream>>>(qh, ql, kh, kl, pos);

  flash_kernel<<<dim3(NTOK/64, NH), blk, 0, stream>>>(qh, ql, kh, kl, vh, vl, aoh, aol);

  gemm_kernel<1,2><<<dim3(16,16,1), blk, 0, stream>>>(aoh, aol, DM, Wo, DM, 0,
      h2, nullptr, DM, hidden, NTOK, DM, nullptr, nullptr, nullptr);

  rmsnorm_kernel<0><<<NTOK, blk, 0, stream>>>(h2, ln2w, hn2, nullptr);

  router_kernel<<<NTOK, blk, 0, stream>>>(h2, ln2w, Wr, ti, tw, cnt);
  offs_kernel<<<1, 64, 0, stream>>>(cnt, offs);
  assign_kernel<<<NTOK/256, blk, 0, stream>>>(ti, tw, offs, cnt2, tokl, slot_of);

  gemm_kernel<0,0><<<dim3(FI/128, 16, NE), blk, 0, stream>>>(hn2, nullptr, DM,
      W1, FI, (long)DM * FI, gate_c, nullptr, FI, nullptr, 0, DM, cnt, offs, tokl);
  gemm_kernel<0,0><<<dim3(FI/128, 16, NE), blk, 0, stream>>>(hn2, nullptr, DM,
      W3, FI, (long)DM * FI, up_c, nullptr, FI, nullptr, 0, DM, cnt, offs, tokl);

  silu_kernel<<<(2 * NTOK * FI / 8) / 256, blk, 0, stream>>>(gate_c, up_c);

  gemm_kernel<0,0><<<dim3(DM/128, 16, NE), blk, 0, stream>>>(gate_c, nullptr, FI,
      W2, DM, (long)FI * DM, down_c, nullptr, DM, nullptr, 0, FI, cnt, offs, nullptr);

  final_kernel<<<NTOK, blk, 0, stream>>>(h2, down_c, slot_of, tw, out);
}